// Round 1
// baseline (1116.906 us; speedup 1.0000x reference)
//
#include <hip/hip_runtime.h>
#include <cstdint>
#include <cmath>

#define L_ 6
#define B_ 16
#define T_ 2048
#define D_ 768
#define V_ 50280
#define BITW ((V_ + 31) / 32)   // 1572 words per batch row

// ---------------- workspace layout (in uint32 units) ----------------
// [0, B_*BITW)                      presence bitmap
// [B_*BITW, +B_)                    per-b distinct counts
// [.., +B_*T_)                      per-b token lists (int)
// [.., +L_*B_*T_)                   sparse logits (float), layout (b*6+l)*T_ + i
// [.., +L_*B_*3)                    per-(l,b) results {nll, acc, valid}
// total = 254832 u32 ~ 1.02 MB

__global__ void k_init(uint32_t* __restrict__ ws) {
    int i = blockIdx.x * 256 + threadIdx.x;
    if (i < B_ * BITW + B_) ws[i] = 0;
}

__global__ void k_build(const int* __restrict__ ids, uint32_t* __restrict__ bitmap,
                        uint32_t* __restrict__ cnt, int* __restrict__ list) {
    int idx = blockIdx.x * 256 + threadIdx.x;   // covers B_*T_ exactly
    int b = idx >> 11;
    int tok = ids[idx];
    uint32_t bit = 1u << (tok & 31);
    uint32_t old = atomicOr(&bitmap[b * BITW + (tok >> 5)], bit);
    if (!(old & bit)) {
        uint32_t p = atomicAdd(&cnt[b], 1u);
        list[b * T_ + (int)p] = tok;
    }
}

// One block handles (b, chunk-of-rows). h vectors for all 6 loops staged in LDS.
// Each wave processes 4 token rows at a time: coalesced float4 loads of W rows,
// 24 fp32 accumulators, butterfly shuffle reduction.
__global__ __launch_bounds__(256) void k_logits(
        const float* __restrict__ x, const float* __restrict__ w,
        const int* __restrict__ as, const uint32_t* __restrict__ cnt,
        const int* __restrict__ list, float* __restrict__ logits) {
    __shared__ float4 hs[L_ * 192];   // 6 * 768 floats = 18432 B
    int b   = blockIdx.x & (B_ - 1);
    int blk = blockIdx.x >> 4;        // 0..31
    int tid = threadIdx.x;

    int t = as[b] - 1;
    if (t < 0) t = 0;
    if (t >= T_) t = T_ - 1;

    for (int j = tid; j < L_ * 192; j += 256) {
        int l = j / 192, c = j % 192;
        const float4* src = (const float4*)(x + ((size_t)(l * B_ + b) * T_ + t) * D_);
        hs[j] = src[c];
    }
    __syncthreads();

    int n = (int)cnt[b];
    int wave = tid >> 6, lane = tid & 63;

    for (int i0 = (blk * 4 + wave) * 4; i0 < n; i0 += 512) {
        int nr = n - i0; if (nr > 4) nr = 4;
        float4 z = make_float4(0.f, 0.f, 0.f, 0.f);
        float4 wv[4][3];
        #pragma unroll
        for (int r = 0; r < 4; ++r) {
            if (r < nr) {
                int tok = list[b * T_ + i0 + r];
                const float4* wr = (const float4*)(w + (size_t)tok * D_);
                wv[r][0] = wr[lane];
                wv[r][1] = wr[64 + lane];
                wv[r][2] = wr[128 + lane];
            } else {
                wv[r][0] = z; wv[r][1] = z; wv[r][2] = z;
            }
        }
        float acc[4][L_];
        #pragma unroll
        for (int r = 0; r < 4; ++r)
            #pragma unroll
            for (int l = 0; l < L_; ++l) acc[r][l] = 0.f;

        #pragma unroll
        for (int l = 0; l < L_; ++l) {
            const float4 h0 = hs[l * 192 + lane];
            const float4 h1 = hs[l * 192 + 64 + lane];
            const float4 h2 = hs[l * 192 + 128 + lane];
            #pragma unroll
            for (int r = 0; r < 4; ++r) {
                float a = acc[r][l];
                a = fmaf(wv[r][0].x, h0.x, a); a = fmaf(wv[r][0].y, h0.y, a);
                a = fmaf(wv[r][0].z, h0.z, a); a = fmaf(wv[r][0].w, h0.w, a);
                a = fmaf(wv[r][1].x, h1.x, a); a = fmaf(wv[r][1].y, h1.y, a);
                a = fmaf(wv[r][1].z, h1.z, a); a = fmaf(wv[r][1].w, h1.w, a);
                a = fmaf(wv[r][2].x, h2.x, a); a = fmaf(wv[r][2].y, h2.y, a);
                a = fmaf(wv[r][2].z, h2.z, a); a = fmaf(wv[r][2].w, h2.w, a);
                acc[r][l] = a;
            }
        }
        #pragma unroll
        for (int r = 0; r < 4; ++r) {
            if (r >= nr) break;
            #pragma unroll
            for (int l = 0; l < L_; ++l) {
                float v = acc[r][l];
                v += __shfl_down(v, 32, 64);
                v += __shfl_down(v, 16, 64);
                v += __shfl_down(v, 8, 64);
                v += __shfl_down(v, 4, 64);
                v += __shfl_down(v, 2, 64);
                v += __shfl_down(v, 1, 64);
                if (lane == 0) logits[((size_t)b * L_ + l) * T_ + i0 + r] = v;
            }
        }
    }
}

__global__ void k_softmax(const float* __restrict__ logits, const int* __restrict__ list,
                          const uint32_t* __restrict__ cnt, const int* __restrict__ ct,
                          const int* __restrict__ as, float* __restrict__ res) {
    int b = blockIdx.x & (B_ - 1);
    int l = blockIdx.x >> 4;
    int tid = threadIdx.x;
    __shared__ float smax[256];
    __shared__ int   stok[256];
    __shared__ float ssum[256];
    __shared__ float s_tgt;
    __shared__ int   s_found;
    if (tid == 0) { s_found = 0; s_tgt = 0.f; }
    __syncthreads();

    int n = (int)cnt[b];
    int tgt = ct[b * L_ + l];
    const float* lg = logits + ((size_t)b * L_ + l) * T_;

    float mx = -INFINITY; int mtok = 0x7fffffff;
    float tv = 0.f; int found = 0;
    for (int i = tid; i < n; i += 256) {
        float v = lg[i];
        int tok = list[b * T_ + i];
        if (v > mx || (v == mx && tok < mtok)) { mx = v; mtok = tok; }
        if (tok == tgt) { tv = v; found = 1; }
    }
    if (found) { s_tgt = tv; s_found = 1; }   // tokens are deduped: at most one writer
    smax[tid] = mx; stok[tid] = mtok;
    __syncthreads();
    for (int s = 128; s > 0; s >>= 1) {
        if (tid < s) {
            float v2 = smax[tid + s]; int t2 = stok[tid + s];
            if (v2 > smax[tid] || (v2 == smax[tid] && t2 < stok[tid])) {
                smax[tid] = v2; stok[tid] = t2;
            }
        }
        __syncthreads();
    }
    float MX = smax[0];
    float s = 0.f;
    for (int i = tid; i < n; i += 256) s += expf(lg[i] - MX);
    ssum[tid] = s;
    __syncthreads();
    for (int st = 128; st > 0; st >>= 1) {
        if (tid < st) ssum[tid] += ssum[tid + st];
        __syncthreads();
    }
    if (tid == 0) {
        int A = as[b];
        int inr = (A >= 1) && (A < T_);
        int valid = s_found && inr;
        float nll = -(s_tgt - MX - logf(ssum[0]));
        float accv = (stok[0] == tgt) ? 1.f : 0.f;
        float* r = res + ((size_t)l * B_ + b) * 3;
        r[0] = valid ? nll : 0.f;
        r[1] = valid ? accv : 0.f;
        r[2] = valid ? 1.f : 0.f;
    }
}

__global__ void k_final(const float* __restrict__ res, float* __restrict__ out) {
    if (threadIdx.x == 0 && blockIdx.x == 0) {
        float suml = 0.f, suma = 0.f, last_acc = 0.f;
        int nh = 0;
        for (int l = 0; l < L_; ++l) {
            float sl = 0.f, sa = 0.f, c = 0.f;
            for (int b = 0; b < B_; ++b) {
                const float* r = res + ((size_t)l * B_ + b) * 3;
                sl += r[0]; sa += r[1]; c += r[2];
            }
            float denom = (c > 1.f) ? c : 1.f;
            float ll = sl / denom;
            float la = sa / denom;
            if (c > 0.f) { suml += ll; suma += la; nh++; }
            if (l == L_ - 1) last_acc = la;
        }
        float dn = (nh > 0) ? (float)nh : 1.f;
        out[0] = suml / dn;
        out[1] = suma / dn;
        out[2] = last_acc;
    }
}

extern "C" void kernel_launch(void* const* d_in, const int* in_sizes, int n_in,
                              void* d_out, int out_size, void* d_ws, size_t ws_size,
                              hipStream_t stream) {
    const float* x   = (const float*)d_in[0];   // (L,B,T,D) f32
    const float* w   = (const float*)d_in[1];   // (V,D) f32
    const int*   ids = (const int*)d_in[2];     // (B,T) i32
    const int*   ct  = (const int*)d_in[3];     // (B,L) i32
    const int*   as  = (const int*)d_in[4];     // (B,) i32
    float* out = (float*)d_out;

    uint32_t* ws = (uint32_t*)d_ws;
    const size_t need_u32 = (size_t)B_ * BITW + B_ + (size_t)B_ * T_
                          + (size_t)L_ * B_ * T_ + (size_t)L_ * B_ * 3;
    if (ws_size < need_u32 * 4) return;  // insufficient scratch — fail cleanly

    uint32_t* bitmap = ws;
    uint32_t* cnt    = ws + (size_t)B_ * BITW;
    int*      list   = (int*)(cnt + B_);
    float*    logits = (float*)(list + (size_t)B_ * T_);
    float*    res    = logits + (size_t)L_ * B_ * T_;

    k_init   <<<dim3((B_ * BITW + B_ + 255) / 256), dim3(256), 0, stream>>>(ws);
    k_build  <<<dim3(B_ * T_ / 256), dim3(256), 0, stream>>>(ids, bitmap, cnt, list);
    k_logits <<<dim3(B_ * 32), dim3(256), 0, stream>>>(x, w, as, cnt, list, logits);
    k_softmax<<<dim3(L_ * B_), dim3(256), 0, stream>>>(logits, list, cnt, ct, as, res);
    k_final  <<<dim3(1), dim3(64), 0, stream>>>(res, out);
}

// Round 2
// 751.427 us; speedup vs baseline: 1.4864x; 1.4864x over previous
//
#include <hip/hip_runtime.h>
#include <cstdint>
#include <cmath>

#define L_ 6
#define B_ 16
#define T_ 2048
#define D_ 768
#define V_ 50280
#define BITW ((V_ + 31) / 32)   // 1572 words per batch row

// ---------------- workspace layout (in uint32 units) ----------------
// [0, B_*BITW)                      presence bitmap
// [B_*BITW, +B_)                    per-b distinct counts
// [.., +B_*T_)                      per-b token lists (int)
// [.., +L_*B_*T_)                   sparse logits (float), layout (b*6+l)*T_ + i
// [.., +L_*B_*3)                    per-(l,b) results {nll, acc, valid}

__global__ void k_init(uint32_t* __restrict__ ws) {
    int i = blockIdx.x * 256 + threadIdx.x;
    if (i < B_ * BITW + B_) ws[i] = 0;
}

// Wave-aggregated dedup append: one atomicAdd per wave instead of per new token.
// Grid covers B_*T_ exactly; each 64-lane wave lies entirely within one b
// (2048 tokens per b, wave-aligned).
__global__ void k_build(const int* __restrict__ ids, uint32_t* __restrict__ bitmap,
                        uint32_t* __restrict__ cnt, int* __restrict__ list) {
    int idx = blockIdx.x * 256 + threadIdx.x;
    int b = idx >> 11;
    int lane = threadIdx.x & 63;
    int tok = ids[idx];
    uint32_t bit = 1u << (tok & 31);
    uint32_t old = atomicOr(&bitmap[b * BITW + (tok >> 5)], bit);
    bool is_new = !(old & bit);
    unsigned long long mask = __ballot(is_new);
    int total = __popcll(mask);
    unsigned long long lt = (lane == 0) ? 0ull : (~0ull >> (64 - lane));
    int prefix = __popcll(mask & lt);
    uint32_t base = 0;
    if (lane == 0 && total > 0) base = atomicAdd(&cnt[b], (uint32_t)total);
    base = (uint32_t)__shfl((int)base, 0, 64);
    if (is_new) list[b * T_ + (int)(base + prefix)] = tok;
}

// One block handles (b, chunk-of-rows). h vectors for all 6 loops staged in LDS.
// Each wave processes 4 token rows at a time: coalesced float4 loads of W rows,
// 24 fp32 accumulators, wave shuffle reduction.
__global__ __launch_bounds__(256) void k_logits(
        const float* __restrict__ x, const float* __restrict__ w,
        const int* __restrict__ as, const uint32_t* __restrict__ cnt,
        const int* __restrict__ list, float* __restrict__ logits) {
    __shared__ float4 hs[L_ * 192];   // 6 * 768 floats = 18432 B
    int b   = blockIdx.x & (B_ - 1);
    int blk = blockIdx.x >> 4;        // 0..31
    int tid = threadIdx.x;

    int t = as[b] - 1;
    if (t < 0) t = 0;
    if (t >= T_) t = T_ - 1;

    for (int j = tid; j < L_ * 192; j += 256) {
        int l = j / 192, c = j % 192;
        const float4* src = (const float4*)(x + ((size_t)(l * B_ + b) * T_ + t) * D_);
        hs[j] = src[c];
    }
    __syncthreads();

    int n = (int)cnt[b];
    int wave = tid >> 6, lane = tid & 63;

    for (int i0 = (blk * 4 + wave) * 4; i0 < n; i0 += 512) {
        int nr = n - i0; if (nr > 4) nr = 4;
        float4 z = make_float4(0.f, 0.f, 0.f, 0.f);
        float4 wv[4][3];
        #pragma unroll
        for (int r = 0; r < 4; ++r) {
            if (r < nr) {
                int tok = list[b * T_ + i0 + r];
                const float4* wr = (const float4*)(w + (size_t)tok * D_);
                wv[r][0] = wr[lane];
                wv[r][1] = wr[64 + lane];
                wv[r][2] = wr[128 + lane];
            } else {
                wv[r][0] = z; wv[r][1] = z; wv[r][2] = z;
            }
        }
        float acc[4][L_];
        #pragma unroll
        for (int r = 0; r < 4; ++r)
            #pragma unroll
            for (int l = 0; l < L_; ++l) acc[r][l] = 0.f;

        #pragma unroll
        for (int l = 0; l < L_; ++l) {
            const float4 h0 = hs[l * 192 + lane];
            const float4 h1 = hs[l * 192 + 64 + lane];
            const float4 h2 = hs[l * 192 + 128 + lane];
            #pragma unroll
            for (int r = 0; r < 4; ++r) {
                float a = acc[r][l];
                a = fmaf(wv[r][0].x, h0.x, a); a = fmaf(wv[r][0].y, h0.y, a);
                a = fmaf(wv[r][0].z, h0.z, a); a = fmaf(wv[r][0].w, h0.w, a);
                a = fmaf(wv[r][1].x, h1.x, a); a = fmaf(wv[r][1].y, h1.y, a);
                a = fmaf(wv[r][1].z, h1.z, a); a = fmaf(wv[r][1].w, h1.w, a);
                a = fmaf(wv[r][2].x, h2.x, a); a = fmaf(wv[r][2].y, h2.y, a);
                a = fmaf(wv[r][2].z, h2.z, a); a = fmaf(wv[r][2].w, h2.w, a);
                acc[r][l] = a;
            }
        }
        #pragma unroll
        for (int r = 0; r < 4; ++r) {
            if (r >= nr) break;
            #pragma unroll
            for (int l = 0; l < L_; ++l) {
                float v = acc[r][l];
                v += __shfl_down(v, 32, 64);
                v += __shfl_down(v, 16, 64);
                v += __shfl_down(v, 8, 64);
                v += __shfl_down(v, 4, 64);
                v += __shfl_down(v, 2, 64);
                v += __shfl_down(v, 1, 64);
                if (lane == 0) logits[((size_t)b * L_ + l) * T_ + i0 + r] = v;
            }
        }
    }
}

__global__ void k_softmax(const float* __restrict__ logits, const int* __restrict__ list,
                          const uint32_t* __restrict__ cnt, const int* __restrict__ ct,
                          const int* __restrict__ as, float* __restrict__ res) {
    int b = blockIdx.x & (B_ - 1);
    int l = blockIdx.x >> 4;
    int tid = threadIdx.x;
    __shared__ float smax[256];
    __shared__ int   stok[256];
    __shared__ float ssum[256];
    __shared__ float s_tgt;
    __shared__ int   s_found;
    if (tid == 0) { s_found = 0; s_tgt = 0.f; }
    __syncthreads();

    int n = (int)cnt[b];
    int tgt = ct[b * L_ + l];
    const float* lg = logits + ((size_t)b * L_ + l) * T_;

    float mx = -INFINITY; int mtok = 0x7fffffff;
    float tv = 0.f; int found = 0;
    for (int i = tid; i < n; i += 256) {
        float v = lg[i];
        int tok = list[b * T_ + i];
        if (v > mx || (v == mx && tok < mtok)) { mx = v; mtok = tok; }
        if (tok == tgt) { tv = v; found = 1; }
    }
    if (found) { s_tgt = tv; s_found = 1; }   // tokens deduped: at most one writer
    smax[tid] = mx; stok[tid] = mtok;
    __syncthreads();
    for (int s = 128; s > 0; s >>= 1) {
        if (tid < s) {
            float v2 = smax[tid + s]; int t2 = stok[tid + s];
            if (v2 > smax[tid] || (v2 == smax[tid] && t2 < stok[tid])) {
                smax[tid] = v2; stok[tid] = t2;
            }
        }
        __syncthreads();
    }
    float MX = smax[0];
    float s = 0.f;
    for (int i = tid; i < n; i += 256) s += expf(lg[i] - MX);
    ssum[tid] = s;
    __syncthreads();
    for (int st = 128; st > 0; st >>= 1) {
        if (tid < st) ssum[tid] += ssum[tid + st];
        __syncthreads();
    }
    if (tid == 0) {
        int A = as[b];
        int inr = (A >= 1) && (A < T_);
        int valid = s_found && inr;
        float nll = -(s_tgt - MX - logf(ssum[0]));
        float accv = (stok[0] == tgt) ? 1.f : 0.f;
        float* r = res + ((size_t)l * B_ + b) * 3;
        r[0] = valid ? nll : 0.f;
        r[1] = valid ? accv : 0.f;
        r[2] = valid ? 1.f : 0.f;
    }
}

// Parallel finalize: thread j = (l,b) loads one triple; reduce over b in LDS;
// threads 0..5 compute per-l means; thread 0 combines.
__global__ void k_final(const float* __restrict__ res, float* __restrict__ out) {
    __shared__ float sl[L_][B_], sa[L_][B_], sc[L_][B_];
    __shared__ float ll[L_], la[L_], lc[L_];
    int tid = threadIdx.x;
    if (tid < L_ * B_) {
        int l = tid / B_, b = tid % B_;
        const float* r = res + (size_t)tid * 3;
        sl[l][b] = r[0]; sa[l][b] = r[1]; sc[l][b] = r[2];
    }
    __syncthreads();
    if (tid < L_) {
        float a = 0.f, c = 0.f, d = 0.f;
        #pragma unroll
        for (int b = 0; b < B_; ++b) { a += sl[tid][b]; c += sa[tid][b]; d += sc[tid][b]; }
        float denom = (d > 1.f) ? d : 1.f;
        ll[tid] = a / denom; la[tid] = c / denom; lc[tid] = d;
    }
    __syncthreads();
    if (tid == 0) {
        float suml = 0.f, suma = 0.f; int nh = 0;
        #pragma unroll
        for (int l = 0; l < L_; ++l) {
            if (lc[l] > 0.f) { suml += ll[l]; suma += la[l]; nh++; }
        }
        float dn = (nh > 0) ? (float)nh : 1.0f;
        out[0] = suml / dn;
        out[1] = suma / dn;
        out[2] = la[L_ - 1];
    }
}

extern "C" void kernel_launch(void* const* d_in, const int* in_sizes, int n_in,
                              void* d_out, int out_size, void* d_ws, size_t ws_size,
                              hipStream_t stream) {
    const float* x   = (const float*)d_in[0];   // (L,B,T,D) f32
    const float* w   = (const float*)d_in[1];   // (V,D) f32
    const int*   ids = (const int*)d_in[2];     // (B,T) i32
    const int*   ct  = (const int*)d_in[3];     // (B,L) i32
    const int*   as  = (const int*)d_in[4];     // (B,) i32
    float* out = (float*)d_out;

    uint32_t* ws = (uint32_t*)d_ws;
    const size_t need_u32 = (size_t)B_ * BITW + B_ + (size_t)B_ * T_
                          + (size_t)L_ * B_ * T_ + (size_t)L_ * B_ * 3;
    if (ws_size < need_u32 * 4) return;

    uint32_t* bitmap = ws;
    uint32_t* cnt    = ws + (size_t)B_ * BITW;
    int*      list   = (int*)(cnt + B_);
    float*    logits = (float*)(list + (size_t)B_ * T_);
    float*    res    = logits + (size_t)L_ * B_ * T_;

    k_init   <<<dim3((B_ * BITW + B_ + 255) / 256), dim3(256), 0, stream>>>(ws);
    k_build  <<<dim3(B_ * T_ / 256), dim3(256), 0, stream>>>(ids, bitmap, cnt, list);
    k_logits <<<dim3(B_ * 32), dim3(256), 0, stream>>>(x, w, as, cnt, list, logits);
    k_softmax<<<dim3(L_ * B_), dim3(256), 0, stream>>>(logits, list, cnt, ct, as, res);
    k_final  <<<dim3(1), dim3(128), 0, stream>>>(res, out);
}